// Round 4
// baseline (1834.205 us; speedup 1.0000x reference)
//
#include <hip/hip_runtime.h>

#define EMB 64
#define INDIM 140
#define NL 4
#define EPS 1e-5f

__device__ __forceinline__ float bnrelu(float v, float sum, float sq, float g, float be, float invN){
  float mu  = sum*invN;
  float var = fmaf(-mu, mu, sq*invN);
  float sc  = g * rsqrtf(var + EPS);
  return fmaxf(fmaf(v - mu, sc, be), 0.f);
}

// ---- fused: deg histogram + edge_attr moments (block-reduced, padded atomics) ----
__global__ __launch_bounds__(256) void k_pass1(const int* __restrict__ dst,
    const float* __restrict__ ea, int E, int* __restrict__ deg, float* __restrict__ est)
{
  __shared__ float ls[9];
  if (threadIdx.x < 9) ls[threadIdx.x] = 0.f;
  __syncthreads();
  int tid = blockIdx.x*blockDim.x + threadIdx.x;
  int stride = gridDim.x*blockDim.x;
  float a0=0,a1=0,a2=0,p00=0,p11=0,p22=0,p01=0,p02=0,p12=0;
  for (int e=tid;e<E;e+=stride){
    atomicAdd(&deg[dst[e]],1);
    float d0=ea[3*e+0], d1=ea[3*e+1], d2=ea[3*e+2];
    a0+=d0;a1+=d1;a2+=d2;
    p00=fmaf(d0,d0,p00); p11=fmaf(d1,d1,p11); p22=fmaf(d2,d2,p22);
    p01=fmaf(d0,d1,p01); p02=fmaf(d0,d2,p02); p12=fmaf(d1,d2,p12);
  }
  #pragma unroll
  for (int off=32; off>0; off>>=1){
    a0+=__shfl_down(a0,off); a1+=__shfl_down(a1,off); a2+=__shfl_down(a2,off);
    p00+=__shfl_down(p00,off); p11+=__shfl_down(p11,off); p22+=__shfl_down(p22,off);
    p01+=__shfl_down(p01,off); p02+=__shfl_down(p02,off); p12+=__shfl_down(p12,off);
  }
  if ((threadIdx.x & 63)==0){
    atomicAdd(&ls[0],a0); atomicAdd(&ls[1],a1); atomicAdd(&ls[2],a2);
    atomicAdd(&ls[3],p00); atomicAdd(&ls[4],p11); atomicAdd(&ls[5],p22);
    atomicAdd(&ls[6],p01); atomicAdd(&ls[7],p02); atomicAdd(&ls[8],p12);
  }
  __syncthreads();
  if (threadIdx.x < 9) atomicAdd(&est[threadIdx.x*16], ls[threadIdx.x]);  // one line per value
}

// ---- hierarchical scan: A) per-1024-block reduce ----
__global__ __launch_bounds__(256) void k_scanA(const int* __restrict__ deg,
    int* __restrict__ bsum, int n)
{
  int b = blockIdx.x, t = threadIdx.x;
  int i0 = b*1024 + t*4;
  int s = 0;
  if (i0+3 < n){ int4 v = *(const int4*)(deg+i0); s = v.x+v.y+v.z+v.w; }
  else { for (int j=0;j<4;j++){ int i=i0+j; if (i<n) s += deg[i]; } }
  #pragma unroll
  for (int off=32;off>0;off>>=1) s += __shfl_down(s, off);
  __shared__ int ws[4];
  if ((t&63)==0) ws[t>>6] = s;
  __syncthreads();
  if (t==0) bsum[b] = ws[0]+ws[1]+ws[2]+ws[3];
}

// ---- B) exclusive scan of block sums (1 wave, chunked) ----
__global__ __launch_bounds__(64) void k_scanB(const int* __restrict__ bsum,
    int* __restrict__ boff, int* __restrict__ rs, int nb, int n)
{
  int t = threadIdx.x;
  int carry = 0;
  for (int base=0; base<nb; base+=64){
    int idx = base + t;
    int v = (idx<nb)? bsum[idx] : 0;
    int x = v;
    #pragma unroll
    for (int off=1;off<64;off<<=1){ int u = __shfl_up(x, off); if (t>=off) x += u; }
    if (idx<nb) boff[idx] = carry + x - v;
    int tot = __shfl(x, 63);
    carry += tot;
  }
  if (t==0) rs[n] = carry;
}

// ---- C) per-block scan; write rs and cur (overwrites deg with start offsets) ----
__global__ __launch_bounds__(256) void k_scanC(int* __restrict__ deg,
    const int* __restrict__ boff, int* __restrict__ rs, int n)
{
  int b = blockIdx.x, t = threadIdx.x;
  int i0 = b*1024 + t*4;
  int a=0,c=0,d=0,e=0;
  if (i0+3 < n){ int4 v = *(const int4*)(deg+i0); a=v.x;c=v.y;d=v.z;e=v.w; }
  else { if(i0<n)a=deg[i0]; if(i0+1<n)c=deg[i0+1]; if(i0+2<n)d=deg[i0+2]; if(i0+3<n)e=deg[i0+3]; }
  int s4 = a+c+d+e;
  int x = s4;
  int lane = t & 63;
  #pragma unroll
  for (int off=1;off<64;off<<=1){ int u = __shfl_up(x, off); if (lane>=off) x += u; }
  int wexcl = x - s4;
  __shared__ int ws[4];
  if (lane==63) ws[t>>6] = x;
  __syncthreads();
  int base = boff[b];
  int wid = t>>6;
  for (int j=0;j<wid;j++) base += ws[j];
  int p = base + wexcl;
  int r0=p, r1=p+a, r2=p+a+c, r3=p+a+c+d;
  if (i0+3 < n){
    *(int4*)(rs+i0)  = make_int4(r0,r1,r2,r3);
    *(int4*)(deg+i0) = make_int4(r0,r1,r2,r3);
  } else {
    if(i0<n){rs[i0]=r0;deg[i0]=r0;} if(i0+1<n){rs[i0+1]=r1;deg[i0+1]=r1;}
    if(i0+2<n){rs[i0+2]=r2;deg[i0+2]=r2;} if(i0+3<n){rs[i0+3]=r3;deg[i0+3]=r3;}
  }
}

// ---- scatter edges into dst-sorted order ----
__global__ __launch_bounds__(256) void k_scatter(const int* __restrict__ src,
    const int* __restrict__ dst, const float* __restrict__ ea, int E,
    int* __restrict__ cur, unsigned short* __restrict__ ss, float* __restrict__ eas)
{
  int tid = blockIdx.x*blockDim.x + threadIdx.x;
  int stride = gridDim.x*blockDim.x;
  for (int e=tid;e<E;e+=stride){
    int d = dst[e];
    int p = atomicAdd(&cur[d], 1);
    ss[p] = (unsigned short)src[e];
    eas[3*p+0] = ea[3*e+0];
    eas[3*p+1] = ea[3*e+1];
    eas[3*p+2] = ea[3*e+2];
  }
}

// ---- fold edge-BN into affine A,c per layer/channel ----
__global__ __launch_bounds__(256) void k_prec(const float* __restrict__ est,
  const float* __restrict__ w1, const float* __restrict__ b1,
  const float* __restrict__ g1, const float* __restrict__ be1,
  float* __restrict__ ac, float invE)
{
  int t = threadIdx.x; int l = t>>6, c = t&63;
  float m0 = est[0]*invE, m1 = est[16]*invE, m2 = est[32]*invE;
  float c00 = est[48]*invE - m0*m0, c11 = est[64]*invE - m1*m1, c22 = est[80]*invE - m2*m2;
  float c01 = est[96]*invE - m0*m1, c02 = est[112]*invE - m0*m2, c12 = est[128]*invE - m1*m2;
  float w0 = w1[(l*3+0)*64+c], w1_ = w1[(l*3+1)*64+c], w2_ = w1[(l*3+2)*64+c];
  float b = b1[l*64+c], g = g1[l*64+c], be = be1[l*64+c];
  float mu = m0*w0 + m1*w1_ + m2*w2_ + b;
  float var = w0*w0*c00 + w1_*w1_*c11 + w2_*w2_*c22
            + 2.f*(w0*w1_*c01 + w0*w2_*c02 + w1_*w2_*c12);
  float sc = g * rsqrtf(var + EPS);
  float* o = ac + l*256 + c*4;
  o[0] = w0*sc; o[1] = w1_*sc; o[2] = w2_*sc; o[3] = (b - mu)*sc + be;
}

// ---- h0 = x @ lin_in_w + b  (4 threads/node, 16 ch each, k-chunked) ----
__global__ __launch_bounds__(64) void k_h0(const float* __restrict__ x,
  const float* __restrict__ w, const float* __restrict__ b, float* __restrict__ h, int n)
{
  int tid = blockIdx.x*64 + threadIdx.x;
  int i = tid >> 2; if (i>=n) return;
  int c0 = (tid & 3) << 4;
  float acc[16];
  #pragma unroll
  for (int j=0;j<16;j++) acc[j] = b[c0+j];
  const float4* xp = (const float4*)(x + (size_t)i*INDIM);
  #pragma unroll 5
  for (int kb=0; kb<INDIM/4; kb++){
    float4 xv = xp[kb];
    const float* wr = w + kb*4*EMB + c0;
    #pragma unroll
    for (int rr=0; rr<4; rr++){
      float xk = (rr==0)?xv.x:(rr==1)?xv.y:(rr==2)?xv.z:xv.w;
      const float4* wq = (const float4*)(wr + rr*EMB);
      #pragma unroll
      for (int q=0;q<4;q++){
        float4 wv = wq[q];
        acc[4*q+0]=fmaf(xk,wv.x,acc[4*q+0]);
        acc[4*q+1]=fmaf(xk,wv.y,acc[4*q+1]);
        acc[4*q+2]=fmaf(xk,wv.z,acc[4*q+2]);
        acc[4*q+3]=fmaf(xk,wv.w,acc[4*q+3]);
      }
    }
  }
  float* hr = h + (size_t)i*EMB + c0;
  #pragma unroll
  for (int q=0;q<4;q++)
    *(float4*)(hr + 4*q) = make_float4(acc[4*q],acc[4*q+1],acc[4*q+2],acc[4*q+3]);
}

// ---- edge encoder sum, wave-per-node, lane=channel ----
__global__ __launch_bounds__(256) void k_edge(const int* __restrict__ rs,
  const float* __restrict__ eas, const float* __restrict__ ac,
  float* __restrict__ r, int n)
{
  int wv = (blockIdx.x*256 + threadIdx.x) >> 6;
  int lane = threadIdx.x & 63;
  if (wv >= n) return;
  float4 a = ((const float4*)ac)[lane];
  int e0 = rs[wv], e1 = rs[wv+1];
  float acc = 0.f;
  int e = e0;
  for (; e+4<=e1; e+=4){
    const float* ep = eas + (size_t)3*e;
    float d00=ep[0], d01=ep[1], d02=ep[2];
    float d10=ep[3], d11=ep[4], d12=ep[5];
    float d20=ep[6], d21=ep[7], d22=ep[8];
    float d30=ep[9], d31=ep[10], d32=ep[11];
    acc += fmaxf(fmaf(d00,a.x,fmaf(d01,a.y,fmaf(d02,a.z,a.w))),0.f);
    acc += fmaxf(fmaf(d10,a.x,fmaf(d11,a.y,fmaf(d12,a.z,a.w))),0.f);
    acc += fmaxf(fmaf(d20,a.x,fmaf(d21,a.y,fmaf(d22,a.z,a.w))),0.f);
    acc += fmaxf(fmaf(d30,a.x,fmaf(d31,a.y,fmaf(d32,a.z,a.w))),0.f);
  }
  for (; e<e1; e++){
    const float* ep = eas + (size_t)3*e;
    acc += fmaxf(fmaf(ep[0],a.x,fmaf(ep[1],a.y,fmaf(ep[2],a.z,a.w))),0.f);
  }
  r[(size_t)wv*EMB + lane] = acc;
}

// ---- neighbor gather, wave-per-node, lane=channel; z = hh[i] + sum hh[src] ----
__global__ __launch_bounds__(256) void k_gather(const float* __restrict__ hh,
  const int* __restrict__ rs, const unsigned short* __restrict__ ss,
  float* __restrict__ z, int n)
{
  int wv = (blockIdx.x*256 + threadIdx.x) >> 6;
  int lane = threadIdx.x & 63;
  if (wv >= n) return;
  int e0 = rs[wv], e1 = rs[wv+1];
  float acc = hh[(size_t)wv*EMB + lane];
  int e = e0;
  for (; e+4<=e1; e+=4){
    int s0=ss[e], s1=ss[e+1], s2=ss[e+2], s3=ss[e+3];
    acc += hh[(size_t)s0*EMB+lane];
    acc += hh[(size_t)s1*EMB+lane];
    acc += hh[(size_t)s2*EMB+lane];
    acc += hh[(size_t)s3*EMB+lane];
  }
  for (; e<e1; e++) acc += hh[(size_t)ss[e]*EMB+lane];
  z[(size_t)wv*EMB + lane] = acc;
}

// ---- hh = h(+bnrelu(y_prev)) + r@w2 + deg*b2 (4 threads/node) ----
__global__ __launch_bounds__(64) void km1(
  float* __restrict__ h, float* __restrict__ yhh, const float* __restrict__ r,
  const int* __restrict__ rs, const float* __restrict__ w2, const float* __restrict__ b2,
  const float* __restrict__ st2, const float* __restrict__ g2, const float* __restrict__ be2,
  int n, int update, float invN)
{
  int tid = blockIdx.x*64 + threadIdx.x;
  int i = tid >> 2; if (i>=n) return;
  int c0 = (tid & 3) << 4;
  float degf = (float)(rs[i+1]-rs[i]);
  float* hp = h + (size_t)i*EMB + c0;
  float* yp = yhh + (size_t)i*EMB + c0;
  float acc[16];
  if (update){
    #pragma unroll
    for (int q=0;q<4;q++){
      int c = c0 + 4*q;
      float4 hv = *(const float4*)(hp + 4*q);
      float4 yv = *(const float4*)(yp + 4*q);
      hv.x += bnrelu(yv.x, st2[c+0], st2[64+c+0], g2[c+0], be2[c+0], invN);
      hv.y += bnrelu(yv.y, st2[c+1], st2[64+c+1], g2[c+1], be2[c+1], invN);
      hv.z += bnrelu(yv.z, st2[c+2], st2[64+c+2], g2[c+2], be2[c+2], invN);
      hv.w += bnrelu(yv.w, st2[c+3], st2[64+c+3], g2[c+3], be2[c+3], invN);
      *(float4*)(hp + 4*q) = hv;
      acc[4*q+0]=fmaf(degf,b2[c+0],hv.x); acc[4*q+1]=fmaf(degf,b2[c+1],hv.y);
      acc[4*q+2]=fmaf(degf,b2[c+2],hv.z); acc[4*q+3]=fmaf(degf,b2[c+3],hv.w);
    }
  } else {
    #pragma unroll
    for (int q=0;q<4;q++){
      int c = c0 + 4*q;
      float4 hv = *(const float4*)(hp + 4*q);
      acc[4*q+0]=fmaf(degf,b2[c+0],hv.x); acc[4*q+1]=fmaf(degf,b2[c+1],hv.y);
      acc[4*q+2]=fmaf(degf,b2[c+2],hv.z); acc[4*q+3]=fmaf(degf,b2[c+3],hv.w);
    }
  }
  const float4* rp = (const float4*)(r + (size_t)i*EMB);
  #pragma unroll 4
  for (int kb=0; kb<16; kb++){
    float4 xv = rp[kb];
    const float* wr = w2 + kb*4*EMB + c0;
    #pragma unroll
    for (int rr=0; rr<4; rr++){
      float xk = (rr==0)?xv.x:(rr==1)?xv.y:(rr==2)?xv.z:xv.w;
      const float4* wq = (const float4*)(wr + rr*EMB);
      #pragma unroll
      for (int q=0;q<4;q++){
        float4 wv = wq[q];
        acc[4*q+0]=fmaf(xk,wv.x,acc[4*q+0]);
        acc[4*q+1]=fmaf(xk,wv.y,acc[4*q+1]);
        acc[4*q+2]=fmaf(xk,wv.z,acc[4*q+2]);
        acc[4*q+3]=fmaf(xk,wv.w,acc[4*q+3]);
      }
    }
  }
  #pragma unroll
  for (int q=0;q<4;q++)
    *(float4*)(yp + 4*q) = make_float4(acc[4*q],acc[4*q+1],acc[4*q+2],acc[4*q+3]);
}

// ---- y = z@w1 + b1 (4 threads/node) ----
__global__ __launch_bounds__(64) void km2(const float* __restrict__ z,
  const float* __restrict__ w1, const float* __restrict__ b1,
  float* __restrict__ yhh, int n)
{
  int tid = blockIdx.x*64 + threadIdx.x;
  int i = tid >> 2; if (i>=n) return;
  int c0 = (tid & 3) << 4;
  float acc[16];
  #pragma unroll
  for (int j=0;j<16;j++) acc[j] = b1[c0+j];
  const float4* zp = (const float4*)(z + (size_t)i*EMB);
  #pragma unroll 4
  for (int kb=0; kb<16; kb++){
    float4 xv = zp[kb];
    const float* wr = w1 + kb*4*EMB + c0;
    #pragma unroll
    for (int rr=0; rr<4; rr++){
      float xk = (rr==0)?xv.x:(rr==1)?xv.y:(rr==2)?xv.z:xv.w;
      const float4* wq = (const float4*)(wr + rr*EMB);
      #pragma unroll
      for (int q=0;q<4;q++){
        float4 wv = wq[q];
        acc[4*q+0]=fmaf(xk,wv.x,acc[4*q+0]);
        acc[4*q+1]=fmaf(xk,wv.y,acc[4*q+1]);
        acc[4*q+2]=fmaf(xk,wv.z,acc[4*q+2]);
        acc[4*q+3]=fmaf(xk,wv.w,acc[4*q+3]);
      }
    }
  }
  float* yp = yhh + (size_t)i*EMB + c0;
  #pragma unroll
  for (int q=0;q<4;q++)
    *(float4*)(yp + 4*q) = make_float4(acc[4*q],acc[4*q+1],acc[4*q+2],acc[4*q+3]);
}

// ---- y = relu(bn1(y)) @ w2m + b2 (4 threads/node, in place) ----
__global__ __launch_bounds__(64) void km3(float* __restrict__ yhh,
  const float* __restrict__ st1, const float* __restrict__ g1, const float* __restrict__ be1,
  const float* __restrict__ w2, const float* __restrict__ b2, int n, float invN)
{
  int tid = blockIdx.x*64 + threadIdx.x;
  int i = tid >> 2; if (i>=n) return;
  int c0 = (tid & 3) << 4;
  const float* yrow = yhh + (size_t)i*EMB;
  float acc[16];
  #pragma unroll
  for (int j=0;j<16;j++) acc[j] = b2[c0+j];
  #pragma unroll 4
  for (int kb=0; kb<16; kb++){
    float4 yv = *(const float4*)(yrow + 4*kb);
    int k = 4*kb;
    float x0 = bnrelu(yv.x, st1[k+0], st1[64+k+0], g1[k+0], be1[k+0], invN);
    float x1 = bnrelu(yv.y, st1[k+1], st1[64+k+1], g1[k+1], be1[k+1], invN);
    float x2 = bnrelu(yv.z, st1[k+2], st1[64+k+2], g1[k+2], be1[k+2], invN);
    float x3 = bnrelu(yv.w, st1[k+3], st1[64+k+3], g1[k+3], be1[k+3], invN);
    const float* wr = w2 + kb*4*EMB + c0;
    #pragma unroll
    for (int rr=0; rr<4; rr++){
      float xk = (rr==0)?x0:(rr==1)?x1:(rr==2)?x2:x3;
      const float4* wq = (const float4*)(wr + rr*EMB);
      #pragma unroll
      for (int q=0;q<4;q++){
        float4 wv = wq[q];
        acc[4*q+0]=fmaf(xk,wv.x,acc[4*q+0]);
        acc[4*q+1]=fmaf(xk,wv.y,acc[4*q+1]);
        acc[4*q+2]=fmaf(xk,wv.z,acc[4*q+2]);
        acc[4*q+3]=fmaf(xk,wv.w,acc[4*q+3]);
      }
    }
  }
  float* yp = (float*)yrow + c0;
  #pragma unroll
  for (int q=0;q<4;q++)
    *(float4*)(yp + 4*q) = make_float4(acc[4*q],acc[4*q+1],acc[4*q+2],acc[4*q+3]);
}

// ---- per-channel sum/sumsq partials (no global atomics) ----
__global__ __launch_bounds__(256) void k_stats(const float* __restrict__ y,
    float* __restrict__ pst, int n)
{
  __shared__ float ls[128];
  int lane = threadIdx.x & 63;
  int wid  = threadIdx.x >> 6;
  int gw = blockIdx.x*4 + wid;
  int nw = gridDim.x*4;
  float s=0.f, q=0.f;
  for (int i=gw; i<n; i+=nw){
    float v = y[(size_t)i*EMB + lane];
    s += v; q = fmaf(v,v,q);
  }
  if (threadIdx.x < 128) ls[threadIdx.x] = 0.f;
  __syncthreads();
  atomicAdd(&ls[lane], s); atomicAdd(&ls[64+lane], q);
  __syncthreads();
  if (threadIdx.x < 128) pst[blockIdx.x*128 + threadIdx.x] = ls[threadIdx.x];
}

__global__ __launch_bounds__(128) void k_red(const float* __restrict__ pst,
    float* __restrict__ st, int nb)
{
  int t = threadIdx.x;
  float s = 0.f;
  for (int b=0;b<nb;b++) s += pst[b*128 + t];
  st[t] = s;
}

// ---- final: h4 = h3 + relu(bn2(y)); out = h4 . wp + bp ----
__global__ __launch_bounds__(64) void k_out(
  const float* __restrict__ h, const float* __restrict__ y,
  const float* __restrict__ st2, const float* __restrict__ g2, const float* __restrict__ be2,
  const float* __restrict__ wp, const float* __restrict__ bp,
  float* __restrict__ out, int n, float invN)
{
  int i = blockIdx.x*64 + threadIdx.x; if (i>=n) return;
  const float* hr = h + (size_t)i*EMB;
  const float* yr = y + (size_t)i*EMB;
  float acc = 0.f;
  #pragma unroll
  for (int q=0;q<16;q++){
    int c0=q*4;
    float4 hv = *(const float4*)(hr+c0);
    float4 yv = *(const float4*)(yr+c0);
    float f0 = hv.x + bnrelu(yv.x, st2[c0+0], st2[64+c0+0], g2[c0+0], be2[c0+0], invN);
    float f1 = hv.y + bnrelu(yv.y, st2[c0+1], st2[64+c0+1], g2[c0+1], be2[c0+1], invN);
    float f2 = hv.z + bnrelu(yv.z, st2[c0+2], st2[64+c0+2], g2[c0+2], be2[c0+2], invN);
    float f3 = hv.w + bnrelu(yv.w, st2[c0+3], st2[64+c0+3], g2[c0+3], be2[c0+3], invN);
    acc = fmaf(f0, wp[c0+0], acc);
    acc = fmaf(f1, wp[c0+1], acc);
    acc = fmaf(f2, wp[c0+2], acc);
    acc = fmaf(f3, wp[c0+3], acc);
  }
  out[i] = acc + bp[0];
}

extern "C" void kernel_launch(void* const* d_in, const int* in_sizes, int n_in,
                              void* d_out, int out_size, void* d_ws, size_t ws_size,
                              hipStream_t stream)
{
  const float* x        = (const float*)d_in[0];
  const int*   ei       = (const int*)d_in[1];
  const float* ea       = (const float*)d_in[2];
  const float* lin_in_w = (const float*)d_in[3];
  const float* lin_in_b = (const float*)d_in[4];
  const float* ee_w1    = (const float*)d_in[5];
  const float* ee_b1    = (const float*)d_in[6];
  const float* ee_g1    = (const float*)d_in[7];
  const float* ee_be1   = (const float*)d_in[8];
  const float* ee_w2    = (const float*)d_in[9];
  const float* ee_b2    = (const float*)d_in[10];
  const float* mlp_w1   = (const float*)d_in[11];
  const float* mlp_b1   = (const float*)d_in[12];
  const float* mlp_g1   = (const float*)d_in[13];
  const float* mlp_be1  = (const float*)d_in[14];
  const float* mlp_w2   = (const float*)d_in[15];
  const float* mlp_b2   = (const float*)d_in[16];
  const float* mlp_g2   = (const float*)d_in[17];
  const float* mlp_be2  = (const float*)d_in[18];
  const float* pred_w   = (const float*)d_in[19];
  const float* pred_b   = (const float*)d_in[20];

  int n = in_sizes[0] / INDIM;
  int E = in_sizes[1] / 2;
  const int* srcp = ei;
  const int* dstp = ei + E;

  char* w = (char*)d_ws;
  auto al = [](size_t o){ return (o + 255) & ~(size_t)255; };
  size_t o = 0;
  int*   deg = (int*)(w + o);  o += (size_t)n*4;  o = al(o);
  float* est = (float*)(w + o); o += 144*4;
  size_t zero_bytes = o;
  o = al(o); int* rs   = (int*)(w + o);   o += (size_t)(n+1)*4;
  o = al(o); int* bsum = (int*)(w + o);   o += 256*4;
  o = al(o); int* boff = (int*)(w + o);   o += 256*4;
  o = al(o); unsigned short* ss = (unsigned short*)(w + o); o += (size_t)E*2;
  o = al(o); float* eas = (float*)(w + o); o += (size_t)E*12;
  o = al(o); float* acb = (float*)(w + o); o += (size_t)NL*256*4;
  o = al(o); float* h   = (float*)(w + o); o += (size_t)n*EMB*4;
  o = al(o); float* yhh = (float*)(w + o); o += (size_t)n*EMB*4;
  o = al(o); float* rz  = (float*)(w + o); o += (size_t)n*EMB*4;
  o = al(o); float* pst = (float*)(w + o); o += 128*128*4;
  o = al(o); float* nst = (float*)(w + o); o += (size_t)NL*256*4;

  (void)hipMemsetAsync(d_ws, 0, zero_bytes, stream);

  int nbChunk = (n + 1023)/1024;
  k_pass1<<<512, 256, 0, stream>>>(dstp, ea, E, deg, est);
  k_scanA<<<nbChunk, 256, 0, stream>>>(deg, bsum, n);
  k_scanB<<<1, 64, 0, stream>>>(bsum, boff, rs, nbChunk, n);
  k_scanC<<<nbChunk, 256, 0, stream>>>(deg, boff, rs, n);
  k_scatter<<<512, 256, 0, stream>>>(srcp, dstp, ea, E, deg /*cur*/, ss, eas);
  k_prec<<<1, 256, 0, stream>>>(est, ee_w1, ee_b1, ee_g1, ee_be1, acb, 1.f/(float)E);

  int nbm = (n*4 + 63)/64;     // 4 threads/node, 64-thread blocks
  int nbw = (n + 3)/4;         // wave per node (4 waves/block)
  int nbo = (n + 63)/64;       // thread per node
  float invN = 1.f/(float)n;
  k_h0<<<nbm, 64, 0, stream>>>(x, lin_in_w, lin_in_b, h, n);

  for (int l=0; l<NL; l++){
    const float* st2p = (l>0) ? (nst + (size_t)(l-1)*256 + 128) : nst;
    const float* g2p  = (l>0) ? (mlp_g2  + (size_t)(l-1)*64) : mlp_g2;
    const float* be2p = (l>0) ? (mlp_be2 + (size_t)(l-1)*64) : mlp_be2;
    k_edge<<<nbw, 256, 0, stream>>>(rs, eas, acb + (size_t)l*256, rz, n);
    km1<<<nbm, 64, 0, stream>>>(h, yhh, rz, rs,
        ee_w2 + (size_t)l*4096, ee_b2 + (size_t)l*64, st2p, g2p, be2p, n, (l>0)?1:0, invN);
    k_gather<<<nbw, 256, 0, stream>>>(yhh, rs, ss, rz, n);
    km2<<<nbm, 64, 0, stream>>>(rz, mlp_w1 + (size_t)l*4096, mlp_b1 + (size_t)l*64, yhh, n);
    k_stats<<<128, 256, 0, stream>>>(yhh, pst, n);
    k_red<<<1, 128, 0, stream>>>(pst, nst + (size_t)l*256, 128);
    km3<<<nbm, 64, 0, stream>>>(yhh, nst + (size_t)l*256,
        mlp_g1 + (size_t)l*64, mlp_be1 + (size_t)l*64,
        mlp_w2 + (size_t)l*4096, mlp_b2 + (size_t)l*64, n, invN);
    k_stats<<<128, 256, 0, stream>>>(yhh, pst, n);
    k_red<<<1, 128, 0, stream>>>(pst, nst + (size_t)l*256 + 128, 128);
  }
  k_out<<<nbo, 64, 0, stream>>>(h, yhh,
      nst + (size_t)(NL-1)*256 + 128, mlp_g2 + (size_t)(NL-1)*64, mlp_be2 + (size_t)(NL-1)*64,
      pred_w, pred_b, (float*)d_out, n, invN);
}

// Round 5
// 1657.538 us; speedup vs baseline: 1.1066x; 1.1066x over previous
//
#include <hip/hip_runtime.h>

#define EMB 64
#define INDIM 140
#define NL 4
#define EPS 1e-5f

__device__ __forceinline__ float bnrelu(float v, float sum, float sq, float g, float be, float invN){
  float mu  = sum*invN;
  float var = fmaf(-mu, mu, sq*invN);
  float sc  = g * rsqrtf(var + EPS);
  return fmaxf(fmaf(v - mu, sc, be), 0.f);
}

// ---- fused: deg histogram + edge_attr moments (block-reduced, padded atomics) ----
__global__ __launch_bounds__(256) void k_pass1(const int* __restrict__ dst,
    const float* __restrict__ ea, int E, int* __restrict__ deg, float* __restrict__ est)
{
  __shared__ float ls[9];
  if (threadIdx.x < 9) ls[threadIdx.x] = 0.f;
  __syncthreads();
  int tid = blockIdx.x*blockDim.x + threadIdx.x;
  int stride = gridDim.x*blockDim.x;
  float a0=0,a1=0,a2=0,p00=0,p11=0,p22=0,p01=0,p02=0,p12=0;
  for (int e=tid;e<E;e+=stride){
    atomicAdd(&deg[dst[e]],1);
    float d0=ea[3*e+0], d1=ea[3*e+1], d2=ea[3*e+2];
    a0+=d0;a1+=d1;a2+=d2;
    p00=fmaf(d0,d0,p00); p11=fmaf(d1,d1,p11); p22=fmaf(d2,d2,p22);
    p01=fmaf(d0,d1,p01); p02=fmaf(d0,d2,p02); p12=fmaf(d1,d2,p12);
  }
  #pragma unroll
  for (int off=32; off>0; off>>=1){
    a0+=__shfl_down(a0,off); a1+=__shfl_down(a1,off); a2+=__shfl_down(a2,off);
    p00+=__shfl_down(p00,off); p11+=__shfl_down(p11,off); p22+=__shfl_down(p22,off);
    p01+=__shfl_down(p01,off); p02+=__shfl_down(p02,off); p12+=__shfl_down(p12,off);
  }
  if ((threadIdx.x & 63)==0){
    atomicAdd(&ls[0],a0); atomicAdd(&ls[1],a1); atomicAdd(&ls[2],a2);
    atomicAdd(&ls[3],p00); atomicAdd(&ls[4],p11); atomicAdd(&ls[5],p22);
    atomicAdd(&ls[6],p01); atomicAdd(&ls[7],p02); atomicAdd(&ls[8],p12);
  }
  __syncthreads();
  if (threadIdx.x < 9) atomicAdd(&est[threadIdx.x*16], ls[threadIdx.x]);  // one line per value
}

// ---- hierarchical scan: A) per-1024-block reduce ----
__global__ __launch_bounds__(256) void k_scanA(const int* __restrict__ deg,
    int* __restrict__ bsum, int n)
{
  int b = blockIdx.x, t = threadIdx.x;
  int i0 = b*1024 + t*4;
  int s = 0;
  if (i0+3 < n){ int4 v = *(const int4*)(deg+i0); s = v.x+v.y+v.z+v.w; }
  else { for (int j=0;j<4;j++){ int i=i0+j; if (i<n) s += deg[i]; } }
  #pragma unroll
  for (int off=32;off>0;off>>=1) s += __shfl_down(s, off);
  __shared__ int ws[4];
  if ((t&63)==0) ws[t>>6] = s;
  __syncthreads();
  if (t==0) bsum[b] = ws[0]+ws[1]+ws[2]+ws[3];
}

// ---- B) exclusive scan of block sums (1 wave, chunked) ----
__global__ __launch_bounds__(64) void k_scanB(const int* __restrict__ bsum,
    int* __restrict__ boff, int* __restrict__ rs, int nb, int n)
{
  int t = threadIdx.x;
  int carry = 0;
  for (int base=0; base<nb; base+=64){
    int idx = base + t;
    int v = (idx<nb)? bsum[idx] : 0;
    int x = v;
    #pragma unroll
    for (int off=1;off<64;off<<=1){ int u = __shfl_up(x, off); if (t>=off) x += u; }
    if (idx<nb) boff[idx] = carry + x - v;
    int tot = __shfl(x, 63);
    carry += tot;
  }
  if (t==0) rs[n] = carry;
}

// ---- C) per-block scan; write rs and cur (overwrites deg with start offsets) ----
__global__ __launch_bounds__(256) void k_scanC(int* __restrict__ deg,
    const int* __restrict__ boff, int* __restrict__ rs, int n)
{
  int b = blockIdx.x, t = threadIdx.x;
  int i0 = b*1024 + t*4;
  int a=0,c=0,d=0,e=0;
  if (i0+3 < n){ int4 v = *(const int4*)(deg+i0); a=v.x;c=v.y;d=v.z;e=v.w; }
  else { if(i0<n)a=deg[i0]; if(i0+1<n)c=deg[i0+1]; if(i0+2<n)d=deg[i0+2]; if(i0+3<n)e=deg[i0+3]; }
  int s4 = a+c+d+e;
  int x = s4;
  int lane = t & 63;
  #pragma unroll
  for (int off=1;off<64;off<<=1){ int u = __shfl_up(x, off); if (lane>=off) x += u; }
  int wexcl = x - s4;
  __shared__ int ws[4];
  if (lane==63) ws[t>>6] = x;
  __syncthreads();
  int base = boff[b];
  int wid = t>>6;
  for (int j=0;j<wid;j++) base += ws[j];
  int p = base + wexcl;
  int r0=p, r1=p+a, r2=p+a+c, r3=p+a+c+d;
  if (i0+3 < n){
    *(int4*)(rs+i0)  = make_int4(r0,r1,r2,r3);
    *(int4*)(deg+i0) = make_int4(r0,r1,r2,r3);
  } else {
    if(i0<n){rs[i0]=r0;deg[i0]=r0;} if(i0+1<n){rs[i0+1]=r1;deg[i0+1]=r1;}
    if(i0+2<n){rs[i0+2]=r2;deg[i0+2]=r2;} if(i0+3<n){rs[i0+3]=r3;deg[i0+3]=r3;}
  }
}

// ---- scatter edges into dst-sorted order ----
__global__ __launch_bounds__(256) void k_scatter(const int* __restrict__ src,
    const int* __restrict__ dst, const float* __restrict__ ea, int E,
    int* __restrict__ cur, unsigned short* __restrict__ ss, float* __restrict__ eas)
{
  int tid = blockIdx.x*blockDim.x + threadIdx.x;
  int stride = gridDim.x*blockDim.x;
  for (int e=tid;e<E;e+=stride){
    int d = dst[e];
    int p = atomicAdd(&cur[d], 1);
    ss[p] = (unsigned short)src[e];
    eas[3*p+0] = ea[3*e+0];
    eas[3*p+1] = ea[3*e+1];
    eas[3*p+2] = ea[3*e+2];
  }
}

// ---- fold edge-BN into affine A,c per layer/channel ----
__global__ __launch_bounds__(256) void k_prec(const float* __restrict__ est,
  const float* __restrict__ w1, const float* __restrict__ b1,
  const float* __restrict__ g1, const float* __restrict__ be1,
  float* __restrict__ ac, float invE)
{
  int t = threadIdx.x; int l = t>>6, c = t&63;
  float m0 = est[0]*invE, m1 = est[16]*invE, m2 = est[32]*invE;
  float c00 = est[48]*invE - m0*m0, c11 = est[64]*invE - m1*m1, c22 = est[80]*invE - m2*m2;
  float c01 = est[96]*invE - m0*m1, c02 = est[112]*invE - m0*m2, c12 = est[128]*invE - m1*m2;
  float w0 = w1[(l*3+0)*64+c], w1_ = w1[(l*3+1)*64+c], w2_ = w1[(l*3+2)*64+c];
  float b = b1[l*64+c], g = g1[l*64+c], be = be1[l*64+c];
  float mu = m0*w0 + m1*w1_ + m2*w2_ + b;
  float var = w0*w0*c00 + w1_*w1_*c11 + w2_*w2_*c22
            + 2.f*(w0*w1_*c01 + w0*w2_*c02 + w1_*w2_*c12);
  float sc = g * rsqrtf(var + EPS);
  float* o = ac + l*256 + c*4;
  o[0] = w0*sc; o[1] = w1_*sc; o[2] = w2_*sc; o[3] = (b - mu)*sc + be;
}

// ---- h0 = x @ lin_in_w + b (thread-per-node, row prefetch, s_load weights) ----
__global__ __launch_bounds__(64,1) void k_h0(const float* __restrict__ x,
  const float* __restrict__ w, const float* __restrict__ b, float* __restrict__ h, int n)
{
  int i = blockIdx.x*64 + threadIdx.x; if (i>=n) return;
  float4 row[35];
  const float4* xp = (const float4*)(x + (size_t)i*INDIM);
  #pragma unroll
  for (int q=0;q<35;q++) row[q] = xp[q];
  float acc[EMB];
  #pragma unroll
  for (int c=0;c<EMB;c++) acc[c] = b[c];
  #pragma unroll
  for (int kb=0; kb<35; kb++){
    const float* wr = w + kb*4*EMB;   // wave-uniform -> scalar loads
    float x0=row[kb].x, x1=row[kb].y, x2=row[kb].z, x3=row[kb].w;
    #pragma unroll
    for (int c=0;c<EMB;c++)
      acc[c] = fmaf(x0, wr[c], fmaf(x1, wr[EMB+c], fmaf(x2, wr[2*EMB+c], fmaf(x3, wr[3*EMB+c], acc[c]))));
  }
  float* hr = h + (size_t)i*EMB;
  #pragma unroll
  for (int q=0;q<16;q++)
    *(float4*)(hr + 4*q) = make_float4(acc[4*q],acc[4*q+1],acc[4*q+2],acc[4*q+3]);
}

// ---- edge encoder sum, wave-per-node, lane=channel ----
__global__ __launch_bounds__(256) void k_edge(const int* __restrict__ rs,
  const float* __restrict__ eas, const float* __restrict__ ac,
  float* __restrict__ r, int n)
{
  int wv = (blockIdx.x*256 + threadIdx.x) >> 6;
  int lane = threadIdx.x & 63;
  if (wv >= n) return;
  float4 a = ((const float4*)ac)[lane];
  int e0 = rs[wv], e1 = rs[wv+1];
  float acc = 0.f;
  int e = e0;
  for (; e+4<=e1; e+=4){
    const float* ep = eas + (size_t)3*e;
    float d00=ep[0], d01=ep[1], d02=ep[2];
    float d10=ep[3], d11=ep[4], d12=ep[5];
    float d20=ep[6], d21=ep[7], d22=ep[8];
    float d30=ep[9], d31=ep[10], d32=ep[11];
    acc += fmaxf(fmaf(d00,a.x,fmaf(d01,a.y,fmaf(d02,a.z,a.w))),0.f);
    acc += fmaxf(fmaf(d10,a.x,fmaf(d11,a.y,fmaf(d12,a.z,a.w))),0.f);
    acc += fmaxf(fmaf(d20,a.x,fmaf(d21,a.y,fmaf(d22,a.z,a.w))),0.f);
    acc += fmaxf(fmaf(d30,a.x,fmaf(d31,a.y,fmaf(d32,a.z,a.w))),0.f);
  }
  for (; e<e1; e++){
    const float* ep = eas + (size_t)3*e;
    acc += fmaxf(fmaf(ep[0],a.x,fmaf(ep[1],a.y,fmaf(ep[2],a.z,a.w))),0.f);
  }
  r[(size_t)wv*EMB + lane] = acc;
}

// ---- neighbor gather, wave-per-node, lane=channel; z = hh[i] + sum hh[src] ----
__global__ __launch_bounds__(256) void k_gather(const float* __restrict__ hh,
  const int* __restrict__ rs, const unsigned short* __restrict__ ss,
  float* __restrict__ z, int n)
{
  int wv = (blockIdx.x*256 + threadIdx.x) >> 6;
  int lane = threadIdx.x & 63;
  if (wv >= n) return;
  int e0 = rs[wv], e1 = rs[wv+1];
  float acc = hh[(size_t)wv*EMB + lane];
  int e = e0;
  for (; e+4<=e1; e+=4){
    int s0=ss[e], s1=ss[e+1], s2=ss[e+2], s3=ss[e+3];
    acc += hh[(size_t)s0*EMB+lane];
    acc += hh[(size_t)s1*EMB+lane];
    acc += hh[(size_t)s2*EMB+lane];
    acc += hh[(size_t)s3*EMB+lane];
  }
  for (; e<e1; e++) acc += hh[(size_t)ss[e]*EMB+lane];
  z[(size_t)wv*EMB + lane] = acc;
}

// ---- hh = h(+bnrelu(y_prev)) + r@w2 + deg*b2 (thread-per-node) ----
__global__ __launch_bounds__(64,1) void km1(
  float* __restrict__ h, float* __restrict__ yhh, const float* __restrict__ r,
  const int* __restrict__ rs, const float* __restrict__ w2, const float* __restrict__ b2,
  const float* __restrict__ st2, const float* __restrict__ g2, const float* __restrict__ be2,
  int n, int update, float invN)
{
  int i = blockIdx.x*64 + threadIdx.x; if (i>=n) return;
  float degf = (float)(rs[i+1]-rs[i]);
  float* hp = h + (size_t)i*EMB;
  float* yp = yhh + (size_t)i*EMB;
  float4 row[16];
  const float4* rp = (const float4*)(r + (size_t)i*EMB);
  #pragma unroll
  for (int q=0;q<16;q++) row[q] = rp[q];
  float acc[EMB];
  if (update){
    #pragma unroll
    for (int q=0;q<16;q++){
      int c = 4*q;
      float4 hv = *(const float4*)(hp + c);
      float4 yv = *(const float4*)(yp + c);
      hv.x += bnrelu(yv.x, st2[c+0], st2[64+c+0], g2[c+0], be2[c+0], invN);
      hv.y += bnrelu(yv.y, st2[c+1], st2[64+c+1], g2[c+1], be2[c+1], invN);
      hv.z += bnrelu(yv.z, st2[c+2], st2[64+c+2], g2[c+2], be2[c+2], invN);
      hv.w += bnrelu(yv.w, st2[c+3], st2[64+c+3], g2[c+3], be2[c+3], invN);
      *(float4*)(hp + c) = hv;
      acc[c+0]=fmaf(degf,b2[c+0],hv.x); acc[c+1]=fmaf(degf,b2[c+1],hv.y);
      acc[c+2]=fmaf(degf,b2[c+2],hv.z); acc[c+3]=fmaf(degf,b2[c+3],hv.w);
    }
  } else {
    #pragma unroll
    for (int q=0;q<16;q++){
      int c = 4*q;
      float4 hv = *(const float4*)(hp + c);
      acc[c+0]=fmaf(degf,b2[c+0],hv.x); acc[c+1]=fmaf(degf,b2[c+1],hv.y);
      acc[c+2]=fmaf(degf,b2[c+2],hv.z); acc[c+3]=fmaf(degf,b2[c+3],hv.w);
    }
  }
  #pragma unroll
  for (int kb=0; kb<16; kb++){
    const float* wr = w2 + kb*4*EMB;   // wave-uniform -> scalar loads
    float x0=row[kb].x, x1=row[kb].y, x2=row[kb].z, x3=row[kb].w;
    #pragma unroll
    for (int c=0;c<EMB;c++)
      acc[c] = fmaf(x0, wr[c], fmaf(x1, wr[EMB+c], fmaf(x2, wr[2*EMB+c], fmaf(x3, wr[3*EMB+c], acc[c]))));
  }
  #pragma unroll
  for (int q=0;q<16;q++)
    *(float4*)(yp + 4*q) = make_float4(acc[4*q],acc[4*q+1],acc[4*q+2],acc[4*q+3]);
}

// ---- y = z@w1 + b1 (thread-per-node) ----
__global__ __launch_bounds__(64,1) void km2(const float* __restrict__ z,
  const float* __restrict__ w1, const float* __restrict__ b1,
  float* __restrict__ yhh, int n)
{
  int i = blockIdx.x*64 + threadIdx.x; if (i>=n) return;
  float4 row[16];
  const float4* zp = (const float4*)(z + (size_t)i*EMB);
  #pragma unroll
  for (int q=0;q<16;q++) row[q] = zp[q];
  float acc[EMB];
  #pragma unroll
  for (int c=0;c<EMB;c++) acc[c] = b1[c];
  #pragma unroll
  for (int kb=0; kb<16; kb++){
    const float* wr = w1 + kb*4*EMB;
    float x0=row[kb].x, x1=row[kb].y, x2=row[kb].z, x3=row[kb].w;
    #pragma unroll
    for (int c=0;c<EMB;c++)
      acc[c] = fmaf(x0, wr[c], fmaf(x1, wr[EMB+c], fmaf(x2, wr[2*EMB+c], fmaf(x3, wr[3*EMB+c], acc[c]))));
  }
  float* yp = yhh + (size_t)i*EMB;
  #pragma unroll
  for (int q=0;q<16;q++)
    *(float4*)(yp + 4*q) = make_float4(acc[4*q],acc[4*q+1],acc[4*q+2],acc[4*q+3]);
}

// ---- y = relu(bn1(y)) @ w2m + b2 (thread-per-node, in place) ----
__global__ __launch_bounds__(64,1) void km3(float* __restrict__ yhh,
  const float* __restrict__ st1, const float* __restrict__ g1, const float* __restrict__ be1,
  const float* __restrict__ w2, const float* __restrict__ b2, int n, float invN)
{
  int i = blockIdx.x*64 + threadIdx.x; if (i>=n) return;
  float* yp = yhh + (size_t)i*EMB;
  float t[EMB];
  #pragma unroll
  for (int q=0;q<16;q++){
    int c = 4*q;
    float4 v = *(const float4*)(yp + c);
    t[c+0]=bnrelu(v.x, st1[c+0], st1[64+c+0], g1[c+0], be1[c+0], invN);
    t[c+1]=bnrelu(v.y, st1[c+1], st1[64+c+1], g1[c+1], be1[c+1], invN);
    t[c+2]=bnrelu(v.z, st1[c+2], st1[64+c+2], g1[c+2], be1[c+2], invN);
    t[c+3]=bnrelu(v.w, st1[c+3], st1[64+c+3], g1[c+3], be1[c+3], invN);
  }
  float acc[EMB];
  #pragma unroll
  for (int c=0;c<EMB;c++) acc[c] = b2[c];
  #pragma unroll
  for (int kb=0; kb<16; kb++){
    const float* wr = w2 + kb*4*EMB;
    float x0=t[4*kb], x1=t[4*kb+1], x2=t[4*kb+2], x3=t[4*kb+3];
    #pragma unroll
    for (int c=0;c<EMB;c++)
      acc[c] = fmaf(x0, wr[c], fmaf(x1, wr[EMB+c], fmaf(x2, wr[2*EMB+c], fmaf(x3, wr[3*EMB+c], acc[c]))));
  }
  #pragma unroll
  for (int q=0;q<16;q++)
    *(float4*)(yp + 4*q) = make_float4(acc[4*q],acc[4*q+1],acc[4*q+2],acc[4*q+3]);
}

// ---- per-channel sum/sumsq partials (no global atomics) ----
__global__ __launch_bounds__(256) void k_stats(const float* __restrict__ y,
    float* __restrict__ pst, int n)
{
  __shared__ float ls[128];
  int lane = threadIdx.x & 63;
  int wid  = threadIdx.x >> 6;
  int gw = blockIdx.x*4 + wid;
  int nw = gridDim.x*4;
  float s=0.f, q=0.f;
  for (int i=gw; i<n; i+=nw){
    float v = y[(size_t)i*EMB + lane];
    s += v; q = fmaf(v,v,q);
  }
  if (threadIdx.x < 128) ls[threadIdx.x] = 0.f;
  __syncthreads();
  atomicAdd(&ls[lane], s); atomicAdd(&ls[64+lane], q);
  __syncthreads();
  if (threadIdx.x < 128) pst[blockIdx.x*128 + threadIdx.x] = ls[threadIdx.x];
}

__global__ __launch_bounds__(128) void k_red(const float* __restrict__ pst,
    float* __restrict__ st, int nb)
{
  int t = threadIdx.x;
  float s = 0.f;
  for (int b=0;b<nb;b++) s += pst[b*128 + t];
  st[t] = s;
}

// ---- final: h4 = h3 + relu(bn2(y)); out = h4 . wp + bp ----
__global__ __launch_bounds__(64) void k_out(
  const float* __restrict__ h, const float* __restrict__ y,
  const float* __restrict__ st2, const float* __restrict__ g2, const float* __restrict__ be2,
  const float* __restrict__ wp, const float* __restrict__ bp,
  float* __restrict__ out, int n, float invN)
{
  int i = blockIdx.x*64 + threadIdx.x; if (i>=n) return;
  const float* hr = h + (size_t)i*EMB;
  const float* yr = y + (size_t)i*EMB;
  float acc = 0.f;
  #pragma unroll
  for (int q=0;q<16;q++){
    int c0=q*4;
    float4 hv = *(const float4*)(hr+c0);
    float4 yv = *(const float4*)(yr+c0);
    float f0 = hv.x + bnrelu(yv.x, st2[c0+0], st2[64+c0+0], g2[c0+0], be2[c0+0], invN);
    float f1 = hv.y + bnrelu(yv.y, st2[c0+1], st2[64+c0+1], g2[c0+1], be2[c0+1], invN);
    float f2 = hv.z + bnrelu(yv.z, st2[c0+2], st2[64+c0+2], g2[c0+2], be2[c0+2], invN);
    float f3 = hv.w + bnrelu(yv.w, st2[c0+3], st2[64+c0+3], g2[c0+3], be2[c0+3], invN);
    acc = fmaf(f0, wp[c0+0], acc);
    acc = fmaf(f1, wp[c0+1], acc);
    acc = fmaf(f2, wp[c0+2], acc);
    acc = fmaf(f3, wp[c0+3], acc);
  }
  out[i] = acc + bp[0];
}

extern "C" void kernel_launch(void* const* d_in, const int* in_sizes, int n_in,
                              void* d_out, int out_size, void* d_ws, size_t ws_size,
                              hipStream_t stream)
{
  const float* x        = (const float*)d_in[0];
  const int*   ei       = (const int*)d_in[1];
  const float* ea       = (const float*)d_in[2];
  const float* lin_in_w = (const float*)d_in[3];
  const float* lin_in_b = (const float*)d_in[4];
  const float* ee_w1    = (const float*)d_in[5];
  const float* ee_b1    = (const float*)d_in[6];
  const float* ee_g1    = (const float*)d_in[7];
  const float* ee_be1   = (const float*)d_in[8];
  const float* ee_w2    = (const float*)d_in[9];
  const float* ee_b2    = (const float*)d_in[10];
  const float* mlp_w1   = (const float*)d_in[11];
  const float* mlp_b1   = (const float*)d_in[12];
  const float* mlp_g1   = (const float*)d_in[13];
  const float* mlp_be1  = (const float*)d_in[14];
  const float* mlp_w2   = (const float*)d_in[15];
  const float* mlp_b2   = (const float*)d_in[16];
  const float* mlp_g2   = (const float*)d_in[17];
  const float* mlp_be2  = (const float*)d_in[18];
  const float* pred_w   = (const float*)d_in[19];
  const float* pred_b   = (const float*)d_in[20];

  int n = in_sizes[0] / INDIM;
  int E = in_sizes[1] / 2;
  const int* srcp = ei;
  const int* dstp = ei + E;

  char* w = (char*)d_ws;
  auto al = [](size_t o){ return (o + 255) & ~(size_t)255; };
  size_t o = 0;
  int*   deg = (int*)(w + o);  o += (size_t)n*4;  o = al(o);
  float* est = (float*)(w + o); o += 144*4;
  size_t zero_bytes = o;
  o = al(o); int* rs   = (int*)(w + o);   o += (size_t)(n+1)*4;
  o = al(o); int* bsum = (int*)(w + o);   o += 256*4;
  o = al(o); int* boff = (int*)(w + o);   o += 256*4;
  o = al(o); unsigned short* ss = (unsigned short*)(w + o); o += (size_t)E*2;
  o = al(o); float* eas = (float*)(w + o); o += (size_t)E*12;
  o = al(o); float* acb = (float*)(w + o); o += (size_t)NL*256*4;
  o = al(o); float* h   = (float*)(w + o); o += (size_t)n*EMB*4;
  o = al(o); float* yhh = (float*)(w + o); o += (size_t)n*EMB*4;
  o = al(o); float* rz  = (float*)(w + o); o += (size_t)n*EMB*4;
  o = al(o); float* pst = (float*)(w + o); o += 256*128*4;
  o = al(o); float* nst = (float*)(w + o); o += (size_t)NL*256*4;

  (void)hipMemsetAsync(d_ws, 0, zero_bytes, stream);

  int nbChunk = (n + 1023)/1024;
  k_pass1<<<512, 256, 0, stream>>>(dstp, ea, E, deg, est);
  k_scanA<<<nbChunk, 256, 0, stream>>>(deg, bsum, n);
  k_scanB<<<1, 64, 0, stream>>>(bsum, boff, rs, nbChunk, n);
  k_scanC<<<nbChunk, 256, 0, stream>>>(deg, boff, rs, n);
  k_scatter<<<1024, 256, 0, stream>>>(srcp, dstp, ea, E, deg /*cur*/, ss, eas);
  k_prec<<<1, 256, 0, stream>>>(est, ee_w1, ee_b1, ee_g1, ee_be1, acb, 1.f/(float)E);

  int nbo = (n + 63)/64;       // thread per node, 64-thread blocks
  int nbw = (n + 3)/4;         // wave per node (4 waves/block)
  float invN = 1.f/(float)n;
  k_h0<<<nbo, 64, 0, stream>>>(x, lin_in_w, lin_in_b, h, n);

  for (int l=0; l<NL; l++){
    const float* st2p = (l>0) ? (nst + (size_t)(l-1)*256 + 128) : nst;
    const float* g2p  = (l>0) ? (mlp_g2  + (size_t)(l-1)*64) : mlp_g2;
    const float* be2p = (l>0) ? (mlp_be2 + (size_t)(l-1)*64) : mlp_be2;
    k_edge<<<nbw, 256, 0, stream>>>(rs, eas, acb + (size_t)l*256, rz, n);
    km1<<<nbo, 64, 0, stream>>>(h, yhh, rz, rs,
        ee_w2 + (size_t)l*4096, ee_b2 + (size_t)l*64, st2p, g2p, be2p, n, (l>0)?1:0, invN);
    k_gather<<<nbw, 256, 0, stream>>>(yhh, rs, ss, rz, n);
    km2<<<nbo, 64, 0, stream>>>(rz, mlp_w1 + (size_t)l*4096, mlp_b1 + (size_t)l*64, yhh, n);
    k_stats<<<256, 256, 0, stream>>>(yhh, pst, n);
    k_red<<<1, 128, 0, stream>>>(pst, nst + (size_t)l*256, 256);
    km3<<<nbo, 64, 0, stream>>>(yhh, nst + (size_t)l*256,
        mlp_g1 + (size_t)l*64, mlp_be1 + (size_t)l*64,
        mlp_w2 + (size_t)l*4096, mlp_b2 + (size_t)l*64, n, invN);
    k_stats<<<256, 256, 0, stream>>>(yhh, pst, n);
    k_red<<<1, 128, 0, stream>>>(pst, nst + (size_t)l*256 + 128, 256);
  }
  k_out<<<nbo, 64, 0, stream>>>(h, yhh,
      nst + (size_t)(NL-1)*256 + 128, mlp_g2 + (size_t)(NL-1)*64, mlp_be2 + (size_t)(NL-1)*64,
      pred_w, pred_b, (float*)d_out, n, invN);
}

// Round 7
// 1222.082 us; speedup vs baseline: 1.5009x; 1.3563x over previous
//
#include <hip/hip_runtime.h>

#define EMB 64
#define INDIM 140
#define NL 4
#define EPS 1e-5f

// padded stats: value v lives at st[v*16] (one 64B line per value)
__device__ __forceinline__ float bnrelu(float v, float sum, float sq, float g, float be, float invN){
  float mu  = sum*invN;
  float var = fmaf(-mu, mu, sq*invN);
  float sc  = g * rsqrtf(var + EPS);
  return fmaxf(fmaf(v - mu, sc, be), 0.f);
}

// ---- fused: deg histogram + edge_attr moments ----
__global__ __launch_bounds__(256) void k_pass1(const int* __restrict__ dst,
    const float* __restrict__ ea, int E, int* __restrict__ deg, float* __restrict__ est)
{
  __shared__ float ls[9];
  if (threadIdx.x < 9) ls[threadIdx.x] = 0.f;
  __syncthreads();
  int tid = blockIdx.x*blockDim.x + threadIdx.x;
  int stride = gridDim.x*blockDim.x;
  float a0=0,a1=0,a2=0,p00=0,p11=0,p22=0,p01=0,p02=0,p12=0;
  for (int e=tid;e<E;e+=stride){
    atomicAdd(&deg[dst[e]],1);
    float d0=ea[3*e+0], d1=ea[3*e+1], d2=ea[3*e+2];
    a0+=d0;a1+=d1;a2+=d2;
    p00=fmaf(d0,d0,p00); p11=fmaf(d1,d1,p11); p22=fmaf(d2,d2,p22);
    p01=fmaf(d0,d1,p01); p02=fmaf(d0,d2,p02); p12=fmaf(d1,d2,p12);
  }
  #pragma unroll
  for (int off=32; off>0; off>>=1){
    a0+=__shfl_down(a0,off); a1+=__shfl_down(a1,off); a2+=__shfl_down(a2,off);
    p00+=__shfl_down(p00,off); p11+=__shfl_down(p11,off); p22+=__shfl_down(p22,off);
    p01+=__shfl_down(p01,off); p02+=__shfl_down(p02,off); p12+=__shfl_down(p12,off);
  }
  if ((threadIdx.x & 63)==0){
    atomicAdd(&ls[0],a0); atomicAdd(&ls[1],a1); atomicAdd(&ls[2],a2);
    atomicAdd(&ls[3],p00); atomicAdd(&ls[4],p11); atomicAdd(&ls[5],p22);
    atomicAdd(&ls[6],p01); atomicAdd(&ls[7],p02); atomicAdd(&ls[8],p12);
  }
  __syncthreads();
  if (threadIdx.x < 9) atomicAdd(&est[threadIdx.x*16], ls[threadIdx.x]);
}

// ---- hierarchical scan ----
__global__ __launch_bounds__(256) void k_scanA(const int* __restrict__ deg,
    int* __restrict__ bsum, int n)
{
  int b = blockIdx.x, t = threadIdx.x;
  int i0 = b*1024 + t*4;
  int s = 0;
  if (i0+3 < n){ int4 v = *(const int4*)(deg+i0); s = v.x+v.y+v.z+v.w; }
  else { for (int j=0;j<4;j++){ int i=i0+j; if (i<n) s += deg[i]; } }
  #pragma unroll
  for (int off=32;off>0;off>>=1) s += __shfl_down(s, off);
  __shared__ int ws[4];
  if ((t&63)==0) ws[t>>6] = s;
  __syncthreads();
  if (t==0) bsum[b] = ws[0]+ws[1]+ws[2]+ws[3];
}

__global__ __launch_bounds__(64) void k_scanB(const int* __restrict__ bsum,
    int* __restrict__ boff, int* __restrict__ rs, int nb, int n)
{
  int t = threadIdx.x;
  int carry = 0;
  for (int base=0; base<nb; base+=64){
    int idx = base + t;
    int v = (idx<nb)? bsum[idx] : 0;
    int x = v;
    #pragma unroll
    for (int off=1;off<64;off<<=1){ int u = __shfl_up(x, off); if (t>=off) x += u; }
    if (idx<nb) boff[idx] = carry + x - v;
    int tot = __shfl(x, 63);
    carry += tot;
  }
  if (t==0) rs[n] = carry;
}

__global__ __launch_bounds__(256) void k_scanC(int* __restrict__ deg,
    const int* __restrict__ boff, int* __restrict__ rs, int n)
{
  int b = blockIdx.x, t = threadIdx.x;
  int i0 = b*1024 + t*4;
  int a=0,c=0,d=0,e=0;
  if (i0+3 < n){ int4 v = *(const int4*)(deg+i0); a=v.x;c=v.y;d=v.z;e=v.w; }
  else { if(i0<n)a=deg[i0]; if(i0+1<n)c=deg[i0+1]; if(i0+2<n)d=deg[i0+2]; if(i0+3<n)e=deg[i0+3]; }
  int s4 = a+c+d+e;
  int x = s4;
  int lane = t & 63;
  #pragma unroll
  for (int off=1;off<64;off<<=1){ int u = __shfl_up(x, off); if (lane>=off) x += u; }
  int wexcl = x - s4;
  __shared__ int ws[4];
  if (lane==63) ws[t>>6] = x;
  __syncthreads();
  int base = boff[b];
  int wid = t>>6;
  for (int j=0;j<wid;j++) base += ws[j];
  int p = base + wexcl;
  int r0=p, r1=p+a, r2=p+a+c, r3=p+a+c+d;
  if (i0+3 < n){
    *(int4*)(rs+i0)  = make_int4(r0,r1,r2,r3);
    *(int4*)(deg+i0) = make_int4(r0,r1,r2,r3);
  } else {
    if(i0<n){rs[i0]=r0;deg[i0]=r0;} if(i0+1<n){rs[i0+1]=r1;deg[i0+1]=r1;}
    if(i0+2<n){rs[i0+2]=r2;deg[i0+2]=r2;} if(i0+3<n){rs[i0+3]=r3;deg[i0+3]=r3;}
  }
}

// ---- scatter edges into dst-sorted 16B records {d0,d1,d2,(float)src} ----
__global__ __launch_bounds__(256) void k_scatter(const int* __restrict__ src,
    const int* __restrict__ dst, const float* __restrict__ ea, int E,
    int* __restrict__ cur, float4* __restrict__ rec)
{
  int tid = blockIdx.x*blockDim.x + threadIdx.x;
  int stride = gridDim.x*blockDim.x;
  for (int e=tid;e<E;e+=stride){
    int d = dst[e];
    int p = atomicAdd(&cur[d], 1);
    rec[p] = make_float4(ea[3*e+0], ea[3*e+1], ea[3*e+2], (float)src[e]);
  }
}

// ---- fold edge-BN into affine A,c per layer/channel ----
__global__ __launch_bounds__(256) void k_prec(const float* __restrict__ est,
  const float* __restrict__ w1, const float* __restrict__ b1,
  const float* __restrict__ g1, const float* __restrict__ be1,
  float* __restrict__ ac, float invE)
{
  int t = threadIdx.x; int l = t>>6, c = t&63;
  float m0 = est[0]*invE, m1 = est[16]*invE, m2 = est[32]*invE;
  float c00 = est[48]*invE - m0*m0, c11 = est[64]*invE - m1*m1, c22 = est[80]*invE - m2*m2;
  float c01 = est[96]*invE - m0*m1, c02 = est[112]*invE - m0*m2, c12 = est[128]*invE - m1*m2;
  float w0 = w1[(l*3+0)*64+c], w1_ = w1[(l*3+1)*64+c], w2_ = w1[(l*3+2)*64+c];
  float b = b1[l*64+c], g = g1[l*64+c], be = be1[l*64+c];
  float mu = m0*w0 + m1*w1_ + m2*w2_ + b;
  float var = w0*w0*c00 + w1_*w1_*c11 + w2_*w2_*c22
            + 2.f*(w0*w1_*c01 + w0*w2_*c02 + w1_*w2_*c12);
  float sc = g * rsqrtf(var + EPS);
  float* o = ac + l*256 + c*4;
  o[0] = w0*sc; o[1] = w1_*sc; o[2] = w2_*sc; o[3] = (b - mu)*sc + be;
}

// ---- h0 = x @ lin_in_w + b (wave-per-node; x row via scalar pipe — x is
// restored to identical bytes every call, so K$ reuse is value-safe) ----
__global__ __launch_bounds__(256) void k_h0(const float* __restrict__ x,
  const float* __restrict__ w, const float* __restrict__ b, float* __restrict__ h, int n)
{
  int wv = (blockIdx.x*256 + threadIdx.x) >> 6;
  int lane = threadIdx.x & 63;
  bool act = (wv < n);
  int i = __builtin_amdgcn_readfirstlane(wv);
  int ii = act ? i : 0;
  const float* xr = x + (size_t)ii*INDIM;   // wave-uniform -> s_load
  const float* wcol = w + lane;
  float accv = b[lane];
  #pragma unroll
  for (int kq=0; kq<INDIM/4; kq++){
    float x0 = xr[4*kq+0], x1 = xr[4*kq+1], x2 = xr[4*kq+2], x3 = xr[4*kq+3];
    accv = fmaf(x0, wcol[(4*kq+0)*EMB], accv);
    accv = fmaf(x1, wcol[(4*kq+1)*EMB], accv);
    accv = fmaf(x2, wcol[(4*kq+2)*EMB], accv);
    accv = fmaf(x3, wcol[(4*kq+3)*EMB], accv);
  }
  if (act) h[(size_t)wv*EMB + lane] = accv;
}

// ---- fused per-layer stage 1: h update + edge encoder + r@w2 -> hh ----
// NOTE: rs/rec are per-call-varying, same-call-written data: read via VECTOR
// loads only (no readfirstlane) — scalar K$ may serve stale lines across calls.
__global__ __launch_bounds__(256) void k_l1(
  float* __restrict__ h, float* __restrict__ hh, const float* __restrict__ yprev,
  const int* __restrict__ rs, const float4* __restrict__ rec,
  const float* __restrict__ ac, const float* __restrict__ w2, const float* __restrict__ b2,
  const float* __restrict__ st2, const float* __restrict__ g2, const float* __restrict__ be2,
  int n, int update, float invN)
{
  __shared__ float ldsr[4][EMB];
  int wv = (blockIdx.x*256 + threadIdx.x) >> 6;
  int wslot = (threadIdx.x >> 6) & 3;
  int lane = threadIdx.x & 63;
  bool act = (wv < n);
  int ii = act ? wv : 0;
  int e0 = rs[ii], e1 = rs[ii+1];           // vector loads, wave-broadcast
  float4 a = ((const float4*)ac)[lane];
  float racc = 0.f;
  int e = e0;
  for (; e+4<=e1; e+=4){
    float4 d0 = rec[e], d1 = rec[e+1], d2 = rec[e+2], d3 = rec[e+3];  // vector
    racc += fmaxf(fmaf(d0.x,a.x,fmaf(d0.y,a.y,fmaf(d0.z,a.z,a.w))),0.f);
    racc += fmaxf(fmaf(d1.x,a.x,fmaf(d1.y,a.y,fmaf(d1.z,a.z,a.w))),0.f);
    racc += fmaxf(fmaf(d2.x,a.x,fmaf(d2.y,a.y,fmaf(d2.z,a.z,a.w))),0.f);
    racc += fmaxf(fmaf(d3.x,a.x,fmaf(d3.y,a.y,fmaf(d3.z,a.z,a.w))),0.f);
  }
  for (; e<e1; e++){
    float4 d0 = rec[e];
    racc += fmaxf(fmaf(d0.x,a.x,fmaf(d0.y,a.y,fmaf(d0.z,a.z,a.w))),0.f);
  }
  ldsr[wslot][lane] = racc;
  float hv = h[(size_t)ii*EMB + lane];
  if (update){
    float yv = yprev[(size_t)ii*EMB + lane];
    hv += bnrelu(yv, st2[lane*16], st2[(64+lane)*16], g2[lane], be2[lane], invN);
    if (act) h[(size_t)wv*EMB + lane] = hv;
  }
  float degf = (float)(e1 - e0);
  float accv = fmaf(degf, b2[lane], hv);
  __syncthreads();
  const float* wcol = w2 + lane;
  const float4* rrow = (const float4*)ldsr[wslot];
  #pragma unroll
  for (int kq=0; kq<16; kq++){
    float4 rv = rrow[kq];
    accv = fmaf(rv.x, wcol[(4*kq+0)*EMB], accv);
    accv = fmaf(rv.y, wcol[(4*kq+1)*EMB], accv);
    accv = fmaf(rv.z, wcol[(4*kq+2)*EMB], accv);
    accv = fmaf(rv.w, wcol[(4*kq+3)*EMB], accv);
  }
  if (act) hh[(size_t)wv*EMB + lane] = accv;
}

// ---- fused per-layer stage 2: gather + (hh+msg)@w1 + b1 -> y ----
__global__ __launch_bounds__(256) void k_l2(
  const float* __restrict__ hh, const int* __restrict__ rs, const float* __restrict__ recw,
  const float* __restrict__ w1, const float* __restrict__ b1,
  float* __restrict__ y, int n)
{
  __shared__ float ldsz[4][EMB];
  int wv = (blockIdx.x*256 + threadIdx.x) >> 6;
  int wslot = (threadIdx.x >> 6) & 3;
  int lane = threadIdx.x & 63;
  bool act = (wv < n);
  int ii = act ? wv : 0;
  int e0 = rs[ii], e1 = rs[ii+1];           // vector loads
  float zc = hh[(size_t)ii*EMB + lane];
  int e = e0;
  for (; e+4<=e1; e+=4){
    int s0 = (int)recw[4*e+3];              // vector 4B loads of rec[].w
    int s1 = (int)recw[4*e+7];
    int s2 = (int)recw[4*e+11];
    int s3 = (int)recw[4*e+15];
    zc += hh[(size_t)s0*EMB + lane];
    zc += hh[(size_t)s1*EMB + lane];
    zc += hh[(size_t)s2*EMB + lane];
    zc += hh[(size_t)s3*EMB + lane];
  }
  for (; e<e1; e++){
    int s0 = (int)recw[4*e+3];
    zc += hh[(size_t)s0*EMB + lane];
  }
  ldsz[wslot][lane] = zc;
  float accv = b1[lane];
  __syncthreads();
  const float* wcol = w1 + lane;
  const float4* zrow = (const float4*)ldsz[wslot];
  #pragma unroll
  for (int kq=0; kq<16; kq++){
    float4 zv = zrow[kq];
    accv = fmaf(zv.x, wcol[(4*kq+0)*EMB], accv);
    accv = fmaf(zv.y, wcol[(4*kq+1)*EMB], accv);
    accv = fmaf(zv.z, wcol[(4*kq+2)*EMB], accv);
    accv = fmaf(zv.w, wcol[(4*kq+3)*EMB], accv);
  }
  if (act) y[(size_t)wv*EMB + lane] = accv;
}

// ---- per-layer stage 3: y = relu(bn1(y)) @ w2m + b2 (in place) ----
__global__ __launch_bounds__(256) void k_l3(float* __restrict__ y,
  const float* __restrict__ st1, const float* __restrict__ g1, const float* __restrict__ be1,
  const float* __restrict__ w2, const float* __restrict__ b2, int n, float invN)
{
  __shared__ float ldst[4][EMB];
  int wv = (blockIdx.x*256 + threadIdx.x) >> 6;
  int wslot = (threadIdx.x >> 6) & 3;
  int lane = threadIdx.x & 63;
  bool act = (wv < n);
  int ii = act ? wv : 0;
  float yv = y[(size_t)ii*EMB + lane];
  float t = bnrelu(yv, st1[lane*16], st1[(64+lane)*16], g1[lane], be1[lane], invN);
  ldst[wslot][lane] = t;
  float accv = b2[lane];
  __syncthreads();
  const float* wcol = w2 + lane;
  const float4* trow = (const float4*)ldst[wslot];
  #pragma unroll
  for (int kq=0; kq<16; kq++){
    float4 tv = trow[kq];
    accv = fmaf(tv.x, wcol[(4*kq+0)*EMB], accv);
    accv = fmaf(tv.y, wcol[(4*kq+1)*EMB], accv);
    accv = fmaf(tv.z, wcol[(4*kq+2)*EMB], accv);
    accv = fmaf(tv.w, wcol[(4*kq+3)*EMB], accv);
  }
  if (act) y[(size_t)wv*EMB + lane] = accv;
}

// ---- per-channel sum/sumsq -> padded atomics into st (st pre-zeroed) ----
__global__ __launch_bounds__(256) void k_stats(const float* __restrict__ y,
    float* __restrict__ st, int n)
{
  __shared__ float ls[128];
  int lane = threadIdx.x & 63;
  int wid  = threadIdx.x >> 6;
  int gw = blockIdx.x*4 + wid;
  int nw = gridDim.x*4;
  float s=0.f, q=0.f;
  for (int i=gw; i<n; i+=nw){
    float v = y[(size_t)i*EMB + lane];
    s += v; q = fmaf(v,v,q);
  }
  if (threadIdx.x < 128) ls[threadIdx.x] = 0.f;
  __syncthreads();
  atomicAdd(&ls[lane], s); atomicAdd(&ls[64+lane], q);
  __syncthreads();
  if (threadIdx.x < 128) atomicAdd(&st[threadIdx.x*16], ls[threadIdx.x]);
}

// ---- final: h4 = h3 + relu(bn2(y)); out = h4 . wp + bp ----
__global__ __launch_bounds__(64) void k_out(
  const float* __restrict__ h, const float* __restrict__ y,
  const float* __restrict__ st2, const float* __restrict__ g2, const float* __restrict__ be2,
  const float* __restrict__ wp, const float* __restrict__ bp,
  float* __restrict__ out, int n, float invN)
{
  int i = blockIdx.x*64 + threadIdx.x; if (i>=n) return;
  const float* hr = h + (size_t)i*EMB;
  const float* yr = y + (size_t)i*EMB;
  float acc = 0.f;
  #pragma unroll
  for (int q=0;q<16;q++){
    int c0=q*4;
    float4 hv = *(const float4*)(hr+c0);
    float4 yv = *(const float4*)(yr+c0);
    float f0 = hv.x + bnrelu(yv.x, st2[(c0+0)*16], st2[(64+c0+0)*16], g2[c0+0], be2[c0+0], invN);
    float f1 = hv.y + bnrelu(yv.y, st2[(c0+1)*16], st2[(64+c0+1)*16], g2[c0+1], be2[c0+1], invN);
    float f2 = hv.z + bnrelu(yv.z, st2[(c0+2)*16], st2[(64+c0+2)*16], g2[c0+2], be2[c0+2], invN);
    float f3 = hv.w + bnrelu(yv.w, st2[(c0+3)*16], st2[(64+c0+3)*16], g2[c0+3], be2[c0+3], invN);
    acc = fmaf(f0, wp[c0+0], acc);
    acc = fmaf(f1, wp[c0+1], acc);
    acc = fmaf(f2, wp[c0+2], acc);
    acc = fmaf(f3, wp[c0+3], acc);
  }
  out[i] = acc + bp[0];
}

extern "C" void kernel_launch(void* const* d_in, const int* in_sizes, int n_in,
                              void* d_out, int out_size, void* d_ws, size_t ws_size,
                              hipStream_t stream)
{
  const float* x        = (const float*)d_in[0];
  const int*   ei       = (const int*)d_in[1];
  const float* ea       = (const float*)d_in[2];
  const float* lin_in_w = (const float*)d_in[3];
  const float* lin_in_b = (const float*)d_in[4];
  const float* ee_w1    = (const float*)d_in[5];
  const float* ee_b1    = (const float*)d_in[6];
  const float* ee_g1    = (const float*)d_in[7];
  const float* ee_be1   = (const float*)d_in[8];
  const float* ee_w2    = (const float*)d_in[9];
  const float* ee_b2    = (const float*)d_in[10];
  const float* mlp_w1   = (const float*)d_in[11];
  const float* mlp_b1   = (const float*)d_in[12];
  const float* mlp_g1   = (const float*)d_in[13];
  const float* mlp_be1  = (const float*)d_in[14];
  const float* mlp_w2   = (const float*)d_in[15];
  const float* mlp_b2   = (const float*)d_in[16];
  const float* mlp_g2   = (const float*)d_in[17];
  const float* mlp_be2  = (const float*)d_in[18];
  const float* pred_w   = (const float*)d_in[19];
  const float* pred_b   = (const float*)d_in[20];

  int n = in_sizes[0] / INDIM;
  int E = in_sizes[1] / 2;
  const int* srcp = ei;
  const int* dstp = ei + E;

  char* w = (char*)d_ws;
  auto al = [](size_t o){ return (o + 255) & ~(size_t)255; };
  size_t o = 0;
  int*   deg = (int*)(w + o);  o += (size_t)n*4;  o = al(o);
  float* est = (float*)(w + o); o += 144*4;  o = al(o);
  float* nst = (float*)(w + o); o += (size_t)NL*2*2048*4;   // per layer: st1[2048], st2[2048] (16-padded)
  size_t zero_bytes = o;
  o = al(o); int* rs   = (int*)(w + o);   o += (size_t)(n+1)*4;
  o = al(o); int* bsum = (int*)(w + o);   o += 256*4;
  o = al(o); int* boff = (int*)(w + o);   o += 256*4;
  o = al(o); float4* rec = (float4*)(w + o); o += (size_t)E*16;
  o = al(o); float* acb = (float*)(w + o); o += (size_t)NL*256*4;
  o = al(o); float* h   = (float*)(w + o); o += (size_t)n*EMB*4;
  o = al(o); float* hhb = (float*)(w + o); o += (size_t)n*EMB*4;
  o = al(o); float* yb  = (float*)(w + o); o += (size_t)n*EMB*4;

  (void)hipMemsetAsync(d_ws, 0, zero_bytes, stream);

  int nbChunk = (n + 1023)/1024;
  k_pass1<<<512, 256, 0, stream>>>(dstp, ea, E, deg, est);
  k_scanA<<<nbChunk, 256, 0, stream>>>(deg, bsum, n);
  k_scanB<<<1, 64, 0, stream>>>(bsum, boff, rs, nbChunk, n);
  k_scanC<<<nbChunk, 256, 0, stream>>>(deg, boff, rs, n);
  k_scatter<<<1024, 256, 0, stream>>>(srcp, dstp, ea, E, deg /*cur*/, rec);
  k_prec<<<1, 256, 0, stream>>>(est, ee_w1, ee_b1, ee_g1, ee_be1, acb, 1.f/(float)E);

  int nbw = (n + 3)/4;         // wave per node, 4 waves/block
  float invN = 1.f/(float)n;
  k_h0<<<nbw, 256, 0, stream>>>(x, lin_in_w, lin_in_b, h, n);

  for (int l=0; l<NL; l++){
    float* st1 = nst + (size_t)l*4096;
    float* st2 = st1 + 2048;
    const float* st2prev = (l>0) ? (nst + (size_t)(l-1)*4096 + 2048) : nst;
    const float* g2p  = (l>0) ? (mlp_g2  + (size_t)(l-1)*64) : mlp_g2;
    const float* be2p = (l>0) ? (mlp_be2 + (size_t)(l-1)*64) : mlp_be2;
    k_l1<<<nbw, 256, 0, stream>>>(h, hhb, yb, rs, rec,
        acb + (size_t)l*256, ee_w2 + (size_t)l*4096, ee_b2 + (size_t)l*64,
        st2prev, g2p, be2p, n, (l>0)?1:0, invN);
    k_l2<<<nbw, 256, 0, stream>>>(hhb, rs, (const float*)rec,
        mlp_w1 + (size_t)l*4096, mlp_b1 + (size_t)l*64, yb, n);
    k_stats<<<256, 256, 0, stream>>>(yb, st1, n);
    k_l3<<<nbw, 256, 0, stream>>>(yb, st1,
        mlp_g1 + (size_t)l*64, mlp_be1 + (size_t)l*64,
        mlp_w2 + (size_t)l*4096, mlp_b2 + (size_t)l*64, n, invN);
    k_stats<<<256, 256, 0, stream>>>(yb, st2, n);
  }
  k_out<<<(n+63)/64, 64, 0, stream>>>(h, yb,
      nst + (size_t)(NL-1)*4096 + 2048, mlp_g2 + (size_t)(NL-1)*64, mlp_be2 + (size_t)(NL-1)*64,
      pred_w, pred_b, (float*)d_out, n, invN);
}